// Round 1
// baseline (175.775 us; speedup 1.0000x reference)
//
#include <hip/hip_runtime.h>

#define NN 20000
#define NE 640000
#define D  128
#define NDPAD 20480
#define CAP 96
#define NPX 2500      // nodes per XCD-range (20000/8)
#define ECHUNK 2000   // edges per chunk; NE/ECHUNK = 320 chunks

using short8 = __attribute__((ext_vector_type(8))) short;
using f32x4  = __attribute__((ext_vector_type(4))) float;

// f32 -> bf16 (RNE) without library types
static __device__ __forceinline__ unsigned short f2bu(float f) {
  unsigned u = __float_as_uint(f);
  unsigned r = (u + 0x7fffu + ((u >> 16) & 1u)) >> 16;
  return (unsigned short)r;
}
static __device__ __forceinline__ unsigned packbf(float a, float b) {
  return (unsigned)f2bu(a) | ((unsigned)f2bu(b) << 16);
}
static __device__ __forceinline__ float bflo(unsigned u) { return __uint_as_float(u << 16); }
static __device__ __forceinline__ float bfhi(unsigned u) { return __uint_as_float(u & 0xffff0000u); }

// ---- fused prep (R8 form: no big LDS — R9 lesson) ----
// [0,80): zero fill | [80,2580): x->bf16 | 2580: zero-row NN | [2581,2965): weights
#define ZB_BLK 80
#define CVT_BLK 2500
#define W_BLK 384
#define PREP_BLK (ZB_BLK + CVT_BLK + 1 + W_BLK)

__global__ __launch_bounds__(256) void prep_kernel(
    const float4* __restrict__ x, uint2* __restrict__ zbA, uint2* __restrict__ zbB,
    const float* __restrict__ wa, const float* __restrict__ wb,
    const float* __restrict__ wc, const float* __restrict__ wd,
    const float* __restrict__ we, const float* __restrict__ wf,
    unsigned short* __restrict__ wt_base,
    int* __restrict__ fill) {
  int b = blockIdx.x;
  int t = threadIdx.x;
  if (b < ZB_BLK) {
    fill[b * 256 + t] = 0;               // covers 20480 exactly
  } else if (b < ZB_BLK + CVT_BLK) {
    int i = (b - ZB_BLK) * 256 + t;      // < 640000 exactly
    float4 v = x[i];
    zbA[i] = make_uint2(packbf(v.x, v.y), packbf(v.z, v.w));
  } else if (b == ZB_BLK + CVT_BLK) {
    if (t < 32)       zbA[NN * 32 + t] = make_uint2(0u, 0u);
    else if (t < 64)  zbB[NN * 32 + (t - 32)] = make_uint2(0u, 0u);
  } else {
    int wb_ = b - (ZB_BLK + CVT_BLK + 1);
    int widx = wb_ >> 6;
    const float* ws[6] = {wa, wb, wc, wd, we, wf};
    const float* w = ws[widx];
    unsigned short* wt = wt_base + (size_t)widx * D * D;
    int idx = (wb_ & 63) * 256 + t;      // 0..16383
    int n = idx >> 7, k = idx & 127;
    wt[idx] = f2bu(w[k * D + n]);
  }
}

// ---- XCD-partitioned ELL scatter ----
// R7/R8: random 2B scatter dirties the whole footprint in EVERY XCD's L2
// (~33 MB writeback for 3.75 MB of data). Fix: block b processes edge chunk
// b>>3 but only dsts in node range (b&7)*NPX..+NPX. With round-robin
// blockIdx->XCD dispatch, each XCD's L2 dirties only its disjoint 470 KB
// slice. If the mapping assumption is wrong this is merely not faster —
// writes are still disjoint per dst, so correctness is unaffected.
__global__ __launch_bounds__(256) void csr_kernel(const int* __restrict__ ei,
                                                  int* __restrict__ fill,
                                                  unsigned short* __restrict__ col_ell) {
  const int xcd = blockIdx.x & 7;
  const int chunk = blockIdx.x >> 3;
  const int nlo = xcd * NPX;
  const int nhi = nlo + NPX;
  const int e0 = chunk * ECHUNK;
  const int4* s4 = reinterpret_cast<const int4*>(ei + e0);
  const int4* d4 = reinterpret_cast<const int4*>(ei + NE + e0);
  for (int q = threadIdx.x; q < ECHUNK / 4; q += 256) {
    int4 d = d4[q];
    int4 s = s4[q];
    if (d.x >= nlo && d.x < nhi) {
      int p = atomicAdd(&fill[d.x], 1);
      if (p < CAP) col_ell[d.x * CAP + p] = (unsigned short)s.x;
    }
    if (d.y >= nlo && d.y < nhi) {
      int p = atomicAdd(&fill[d.y], 1);
      if (p < CAP) col_ell[d.y * CAP + p] = (unsigned short)s.y;
    }
    if (d.z >= nlo && d.z < nhi) {
      int p = atomicAdd(&fill[d.z], 1);
      if (p < CAP) col_ell[d.z * CAP + p] = (unsigned short)s.z;
    }
    if (d.w >= nlo && d.w < nhi) {
      int p = atomicAdd(&fill[d.w], 1);
      if (p < CAP) col_ell[d.w * CAP + p] = (unsigned short)s.w;
    }
  }
}

// ---- degree-balanced node ordering (R10) ----
// Theory: layer blocks barrier on max(deg) over their 16 random nodes
// (E[max16 Bin(32)] ~ 45 vs mean 32) and each wave pays max(dgA,dgB) for
// its pair. Counting-sort nodes by degree DESCENDING so (a) nodes within a
// block have ~equal degree -> no intra-block barrier waste, (b) paired
// nodes have equal degree -> no padded zero-row gathers, (c) heavy blocks
// dispatch first -> cheap blocks fill the scheduling tail.
// Single block: 20000 nodes, 256-bin histogram, serial scan, atomic scatter.
__global__ __launch_bounds__(1024) void order_kernel(const int* __restrict__ fill,
                                                     int* __restrict__ order) {
  __shared__ int hist[256];
  __shared__ int base[256];
  const int t = threadIdx.x;
  if (t < 256) hist[t] = 0;
  __syncthreads();
  for (int i = t; i < NN; i += 1024) {
    int d = min(fill[i], 255);
    atomicAdd(&hist[d], 1);
  }
  __syncthreads();
  if (t == 0) {
    int acc = 0;
    for (int b = 255; b >= 0; --b) { base[b] = acc; acc += hist[b]; }
  }
  __syncthreads();
  if (t < 256) hist[t] = 0;   // reuse as per-bin cursors
  __syncthreads();
  for (int i = t; i < NN; i += 1024) {
    int d = min(fill[i], 255);
    int pos = base[d] + atomicAdd(&hist[d], 1);
    order[pos] = i;
  }
}

// ---- fused layer: agg + 2-GEMM MLP. 16 nodes/block, 8 waves. (R8 form) ----
// R10: nodes are taken through the degree-sorted permutation `order`; all
// node-indexed arrays (zb4 self row, deg, col_ell, output row) use the
// permuted node id. Block-local row r (Ht/H2/MFMA) stays 0..15.
__global__ __launch_bounds__(512, 4) void layer_kernel(
    const uint4* __restrict__ zb4,             // [NN+1][16] (row NN = zeros)
    const int* __restrict__ deg,
    const unsigned short* __restrict__ col_ell,
    const int* __restrict__ order,             // degree-sorted node ids
    const unsigned short* __restrict__ w1t,    // [n][k] bf16
    const float* __restrict__ b1,
    const unsigned short* __restrict__ w2t,    // [n][k] bf16
    const float* __restrict__ b2,
    unsigned short* __restrict__ zb_out,       // bf16 out (layers 0,1)
    float* __restrict__ f_out) {               // f32 out (last layer) or null
  __shared__ alignas(16) unsigned char Ht[16 * 256];   // h = z+agg, swizzled bf16
  __shared__ alignas(16) unsigned char H2[16 * 256];   // relu(h@w1+b1), swizzled
  const int lane = threadIdx.x & 63;
  const int wv = threadIdx.x >> 6;             // 0..7
  const int nb = blockIdx.x * 16;
  const int hf = lane >> 4;        // which edge within a 4-edge chunk
  const int cs = lane & 15;        // 16B column-slot within a 256B row

  // ---- aggregation: wave wv owns rows {2wv, 2wv+1}, interleaved ----
  {
    const int r0 = wv * 2, r1 = r0 + 1;
    const int nodeA = __builtin_amdgcn_readfirstlane(order[nb + r0]);
    const int nodeB = __builtin_amdgcn_readfirstlane(order[nb + r1]);
    const int dgA = deg[nodeA], dgB = deg[nodeB];
    const unsigned short* cbA = col_ell + nodeA * CAP;
    const unsigned short* cbB = col_ell + nodeB * CAP;
    const int nch = (max(dgA, dgB) + 3) >> 2;
    float a0 = 0.f, a1 = 0.f, a2 = 0.f, a3 = 0.f;
    float a4 = 0.f, a5 = 0.f, a6 = 0.f, a7 = 0.f;
    float c0 = 0.f, c1 = 0.f, c2 = 0.f, c3 = 0.f;
    float c4 = 0.f, c5 = 0.f, c6 = 0.f, c7 = 0.f;
#pragma unroll 4
    for (int c = 0; c < nch; ++c) {
      int slot = c * 4 + hf;
      int idxA = (slot < dgA) ? (int)cbA[slot] : NN;
      int idxB = (slot < dgB) ? (int)cbB[slot] : NN;
      uint4 u = zb4[(size_t)idxA * 16 + cs];
      uint4 v = zb4[(size_t)idxB * 16 + cs];
      a0 += bflo(u.x); a1 += bfhi(u.x);
      a2 += bflo(u.y); a3 += bfhi(u.y);
      a4 += bflo(u.z); a5 += bfhi(u.z);
      a6 += bflo(u.w); a7 += bfhi(u.w);
      c0 += bflo(v.x); c1 += bfhi(v.x);
      c2 += bflo(v.y); c3 += bfhi(v.y);
      c4 += bflo(v.z); c5 += bfhi(v.z);
      c6 += bflo(v.w); c7 += bfhi(v.w);
    }
    // butterfly: lanes l, l^16, l^32, l^48 share columns -> all lanes get totals
    a0 += __shfl_xor(a0, 16); a1 += __shfl_xor(a1, 16);
    a2 += __shfl_xor(a2, 16); a3 += __shfl_xor(a3, 16);
    a4 += __shfl_xor(a4, 16); a5 += __shfl_xor(a5, 16);
    a6 += __shfl_xor(a6, 16); a7 += __shfl_xor(a7, 16);
    c0 += __shfl_xor(c0, 16); c1 += __shfl_xor(c1, 16);
    c2 += __shfl_xor(c2, 16); c3 += __shfl_xor(c3, 16);
    c4 += __shfl_xor(c4, 16); c5 += __shfl_xor(c5, 16);
    c6 += __shfl_xor(c6, 16); c7 += __shfl_xor(c7, 16);
    a0 += __shfl_xor(a0, 32); a1 += __shfl_xor(a1, 32);
    a2 += __shfl_xor(a2, 32); a3 += __shfl_xor(a3, 32);
    a4 += __shfl_xor(a4, 32); a5 += __shfl_xor(a5, 32);
    a6 += __shfl_xor(a6, 32); a7 += __shfl_xor(a7, 32);
    c0 += __shfl_xor(c0, 32); c1 += __shfl_xor(c1, 32);
    c2 += __shfl_xor(c2, 32); c3 += __shfl_xor(c3, 32);
    c4 += __shfl_xor(c4, 32); c5 += __shfl_xor(c5, 32);
    c6 += __shfl_xor(c6, 32); c7 += __shfl_xor(c7, 32);
    // self terms
    uint4 sA = zb4[(size_t)nodeA * 16 + cs];
    uint4 sB = zb4[(size_t)nodeB * 16 + cs];
    a0 += bflo(sA.x); a1 += bfhi(sA.x);
    a2 += bflo(sA.y); a3 += bfhi(sA.y);
    a4 += bflo(sA.z); a5 += bfhi(sA.z);
    a6 += bflo(sA.w); a7 += bfhi(sA.w);
    c0 += bflo(sB.x); c1 += bfhi(sB.x);
    c2 += bflo(sB.y); c3 += bfhi(sB.y);
    c4 += bflo(sB.z); c5 += bfhi(sB.z);
    c6 += bflo(sB.w); c7 += bfhi(sB.w);
    if (hf == 0) {
      uint4 p;
      p.x = packbf(a0, a1); p.y = packbf(a2, a3);
      p.z = packbf(a4, a5); p.w = packbf(a6, a7);
      *reinterpret_cast<uint4*>(&Ht[(r0 * 256 + cs * 16) ^ ((r0 & 7) << 4)]) = p;
    } else if (hf == 1) {
      uint4 p;
      p.x = packbf(c0, c1); p.y = packbf(c2, c3);
      p.z = packbf(c4, c5); p.w = packbf(c6, c7);
      *reinterpret_cast<uint4*>(&Ht[(r1 * 256 + cs * 16) ^ ((r1 & 7) << 4)]) = p;
    }
  }
  __syncthreads();

  const int ar = lane & 15;        // A row / B col / C col
  const int kg = lane >> 4;        // k-group 0..3
  const int crb = kg * 4;          // C/D row base

  // ---- GEMM1: wave's N-tile nt = wv ----
  short8 a[4];
#pragma unroll
  for (int ks = 0; ks < 4; ++ks) {
    int byte = (ar * 256 + (ks * 32 + kg * 8) * 2) ^ ((ar & 7) << 4);
    a[ks] = *reinterpret_cast<const short8*>(&Ht[byte]);
  }
  f32x4 acc = (f32x4){0.f, 0.f, 0.f, 0.f};
#pragma unroll
  for (int ks = 0; ks < 4; ++ks) {
    short8 b = *reinterpret_cast<const short8*>(&w1t[(wv * 16 + ar) * D + ks * 32 + kg * 8]);
    acc = __builtin_amdgcn_mfma_f32_16x16x32_bf16(a[ks], b, acc, 0, 0, 0);
  }
  {
    int col = wv * 16 + ar;
    float bias = b1[col];
#pragma unroll
    for (int j = 0; j < 4; ++j) {
      int r = crb + j;
      float v = fmaxf(acc[j] + bias, 0.f);
      int byte = (r * 256 + col * 2) ^ ((r & 7) << 4);
      *reinterpret_cast<unsigned short*>(&H2[byte]) = f2bu(v);
    }
  }
  __syncthreads();

  // ---- GEMM2 ----
  short8 a2[4];
#pragma unroll
  for (int ks = 0; ks < 4; ++ks) {
    int byte = (ar * 256 + (ks * 32 + kg * 8) * 2) ^ ((ar & 7) << 4);
    a2[ks] = *reinterpret_cast<const short8*>(&H2[byte]);
  }
  acc = (f32x4){0.f, 0.f, 0.f, 0.f};
#pragma unroll
  for (int ks = 0; ks < 4; ++ks) {
    short8 b = *reinterpret_cast<const short8*>(&w2t[(wv * 16 + ar) * D + ks * 32 + kg * 8]);
    acc = __builtin_amdgcn_mfma_f32_16x16x32_bf16(a2[ks], b, acc, 0, 0, 0);
  }
  {
    int col = wv * 16 + ar;
    float bias = b2[col];
    if (f_out != nullptr) {
#pragma unroll
      for (int j = 0; j < 4; ++j) {
        int row = order[nb + crb + j];
        f_out[(size_t)row * D + col] = fmaxf(acc[j] + bias, 0.f);
      }
    } else {
#pragma unroll
      for (int j = 0; j < 4; ++j) {
        int row = order[nb + crb + j];
        zb_out[(size_t)row * D + col] = f2bu(fmaxf(acc[j] + bias, 0.f));
      }
    }
  }
}

extern "C" void kernel_launch(void* const* d_in, const int* in_sizes, int n_in,
                              void* d_out, int out_size, void* d_ws, size_t ws_size,
                              hipStream_t stream) {
  const float* x = (const float*)d_in[0];
  const int* ei = (const int*)d_in[1];
  const float* w1[3] = {(const float*)d_in[2], (const float*)d_in[6], (const float*)d_in[10]};
  const float* b1[3] = {(const float*)d_in[3], (const float*)d_in[7], (const float*)d_in[11]};
  const float* w2[3] = {(const float*)d_in[4], (const float*)d_in[8], (const float*)d_in[12]};
  const float* b2[3] = {(const float*)d_in[5], (const float*)d_in[9], (const float*)d_in[13]};
  float* out = (float*)d_out;

  char* wsb = (char*)d_ws;
  size_t off = 0;
  auto alloc = [&](size_t bytes) -> void* {
    void* p = wsb + off;
    off += (bytes + 255) & ~(size_t)255;
    return p;
  };
  unsigned short* zbA = (unsigned short*)alloc((size_t)(NN + 1) * D * 2);
  unsigned short* zbB = (unsigned short*)alloc((size_t)(NN + 1) * D * 2);
  unsigned short* wt  = (unsigned short*)alloc((size_t)6 * D * D * 2);
  int* fill = (int*)alloc((size_t)NDPAD * 4);
  unsigned short* col_ell = (unsigned short*)alloc((size_t)NDPAD * CAP * 2);
  int* order = (int*)alloc((size_t)NDPAD * 4);

  prep_kernel<<<PREP_BLK, 256, 0, stream>>>(
      (const float4*)x, (uint2*)zbA, (uint2*)zbB, w1[0], w2[0], w1[1], w2[1], w1[2], w2[2],
      wt, fill);
  csr_kernel<<<(NE / ECHUNK) * 8, 256, 0, stream>>>(ei, fill, col_ell);
  order_kernel<<<1, 1024, 0, stream>>>(fill, order);

  const unsigned short* zin = zbA;
  unsigned short* zout = zbB;
  for (int l = 0; l < 3; ++l) {
    layer_kernel<<<NN / 16, 512, 0, stream>>>(
        (const uint4*)zin, fill, col_ell, order,
        wt + (size_t)(2 * l) * D * D, b1[l],
        wt + (size_t)(2 * l + 1) * D * D, b2[l],
        zout, (l == 2) ? out : nullptr);
    const unsigned short* t = zin;
    zin = zout;
    zout = (unsigned short*)t;
  }
}

// Round 2
// 163.509 us; speedup vs baseline: 1.0750x; 1.0750x over previous
//
#include <hip/hip_runtime.h>

#define NN 20000
#define NE 640000
#define D  128
#define NDPAD 20480
#define CAP 96
#define NPX 2500      // nodes per XCD-range (20000/8)
#define ECHUNK 2000   // edges per chunk; NE/ECHUNK = 320 chunks

using short8 = __attribute__((ext_vector_type(8))) short;
using f32x4  = __attribute__((ext_vector_type(4))) float;

// f32 -> bf16 (RNE) without library types
static __device__ __forceinline__ unsigned short f2bu(float f) {
  unsigned u = __float_as_uint(f);
  unsigned r = (u + 0x7fffu + ((u >> 16) & 1u)) >> 16;
  return (unsigned short)r;
}
static __device__ __forceinline__ unsigned packbf(float a, float b) {
  return (unsigned)f2bu(a) | ((unsigned)f2bu(b) << 16);
}
static __device__ __forceinline__ float bflo(unsigned u) { return __uint_as_float(u << 16); }
static __device__ __forceinline__ float bfhi(unsigned u) { return __uint_as_float(u & 0xffff0000u); }

// ---- fused prep (R8 form: no big LDS — R9 lesson) ----
// [0,80): zero fill | [80,2580): x->bf16 | 2580: zero-row NN | [2581,2965): weights
#define ZB_BLK 80
#define CVT_BLK 2500
#define W_BLK 384
#define PREP_BLK (ZB_BLK + CVT_BLK + 1 + W_BLK)

__global__ __launch_bounds__(256) void prep_kernel(
    const float4* __restrict__ x, uint2* __restrict__ zbA, uint2* __restrict__ zbB,
    const float* __restrict__ wa, const float* __restrict__ wb,
    const float* __restrict__ wc, const float* __restrict__ wd,
    const float* __restrict__ we, const float* __restrict__ wf,
    unsigned short* __restrict__ wt_base,
    int* __restrict__ fill) {
  int b = blockIdx.x;
  int t = threadIdx.x;
  if (b < ZB_BLK) {
    fill[b * 256 + t] = 0;               // covers 20480 exactly
  } else if (b < ZB_BLK + CVT_BLK) {
    int i = (b - ZB_BLK) * 256 + t;      // < 640000 exactly
    float4 v = x[i];
    zbA[i] = make_uint2(packbf(v.x, v.y), packbf(v.z, v.w));
  } else if (b == ZB_BLK + CVT_BLK) {
    if (t < 32)       zbA[NN * 32 + t] = make_uint2(0u, 0u);
    else if (t < 64)  zbB[NN * 32 + (t - 32)] = make_uint2(0u, 0u);
  } else {
    int wb_ = b - (ZB_BLK + CVT_BLK + 1);
    int widx = wb_ >> 6;
    const float* ws[6] = {wa, wb, wc, wd, we, wf};
    const float* w = ws[widx];
    unsigned short* wt = wt_base + (size_t)widx * D * D;
    int idx = (wb_ & 63) * 256 + t;      // 0..16383
    int n = idx >> 7, k = idx & 127;
    wt[idx] = f2bu(w[k * D + n]);
  }
}

// ---- XCD-partitioned ELL scatter ----
// R7/R8: random 2B scatter dirties the whole footprint in EVERY XCD's L2
// (~33 MB writeback for 3.75 MB of data). Fix: block b processes edge chunk
// b>>3 but only dsts in node range (b&7)*NPX..+NPX.
__global__ __launch_bounds__(256) void csr_kernel(const int* __restrict__ ei,
                                                  int* __restrict__ fill,
                                                  unsigned short* __restrict__ col_ell) {
  const int xcd = blockIdx.x & 7;
  const int chunk = blockIdx.x >> 3;
  const int nlo = xcd * NPX;
  const int nhi = nlo + NPX;
  const int e0 = chunk * ECHUNK;
  const int4* s4 = reinterpret_cast<const int4*>(ei + e0);
  const int4* d4 = reinterpret_cast<const int4*>(ei + NE + e0);
  for (int q = threadIdx.x; q < ECHUNK / 4; q += 256) {
    int4 d = d4[q];
    int4 s = s4[q];
    if (d.x >= nlo && d.x < nhi) {
      int p = atomicAdd(&fill[d.x], 1);
      if (p < CAP) col_ell[d.x * CAP + p] = (unsigned short)s.x;
    }
    if (d.y >= nlo && d.y < nhi) {
      int p = atomicAdd(&fill[d.y], 1);
      if (p < CAP) col_ell[d.y * CAP + p] = (unsigned short)s.y;
    }
    if (d.z >= nlo && d.z < nhi) {
      int p = atomicAdd(&fill[d.z], 1);
      if (p < CAP) col_ell[d.z * CAP + p] = (unsigned short)s.z;
    }
    if (d.w >= nlo && d.w < nhi) {
      int p = atomicAdd(&fill[d.w], 1);
      if (p < CAP) col_ell[d.w * CAP + p] = (unsigned short)s.w;
    }
  }
}

// ---- R11: per-node neighbor-list ascending sort (gather locality) ----
// Theory: z-table (5.12 MB) slightly exceeds a 4 MB XCD L2 and gathers are
// uniform-random -> every XCD thrashes, gathers served at L3 latency
// (~MSHR-bound, ~4 TB/s effective). Sorting each node's list makes every
// wave sweep the table in ascending address order; concurrently-resident
// blocks sweep together, so the hot window (~1-2 MB) stays L2-resident in
// every XCD. Sum order change is harmless (f32 accumulation, loose tol).
// One wave per node; 128-element bitonic sort held in 2 regs/lane.
__global__ __launch_bounds__(512) void sort_kernel(const int* __restrict__ fill,
                                                   unsigned short* __restrict__ col_ell) {
  const int wv = threadIdx.x >> 6;
  const int lane = threadIdx.x & 63;
  const int node = blockIdx.x * 8 + wv;          // 2500*8 = 20000 exactly
  const int dg = min(fill[node], CAP);
  unsigned short* cb = col_ell + node * CAP;
  // element e = r*64 + lane; pad with 0xFFFF (> any node id) -> sorts last
  int v0 = (lane < dg) ? (int)cb[lane] : 0xFFFF;
  int v1 = (64 + lane < dg) ? (int)cb[64 + lane] : 0xFFFF;
  // Batcher bitonic, n=128, ascending. Note: j < k always, and e^j flips a
  // bit below k's bit, so (e & k) is pair-uniform.
  for (int k = 2; k <= 128; k <<= 1) {
    for (int j = k >> 1; j >= 1; j >>= 1) {
      if (j == 64) {
        // partner across the two regs (e and e+64); k==128 here -> ascending
        int lo = min(v0, v1), hi = max(v0, v1);
        v0 = lo; v1 = hi;
      } else {
        {
          int o = __shfl_xor(v0, j);
          int e = lane;
          bool up = ((e & k) == 0);
          bool takeMin = (((e & j) == 0) == up);
          v0 = takeMin ? min(v0, o) : max(v0, o);
        }
        {
          int o = __shfl_xor(v1, j);
          int e = 64 + lane;
          bool up = ((e & k) == 0);
          bool takeMin = (((e & j) == 0) == up);
          v1 = takeMin ? min(v1, o) : max(v1, o);
        }
      }
    }
  }
  cb[lane] = (unsigned short)v0;                 // slots 0..63
  if (lane < CAP - 64) cb[64 + lane] = (unsigned short)v1;  // slots 64..95
}

// ---- fused layer: agg + 2-GEMM MLP. 16 nodes/block, 8 waves. (R8 form) ----
__global__ __launch_bounds__(512, 4) void layer_kernel(
    const uint4* __restrict__ zb4,             // [NN+1][16] (row NN = zeros)
    const int* __restrict__ deg,
    const unsigned short* __restrict__ col_ell,
    const unsigned short* __restrict__ w1t,    // [n][k] bf16
    const float* __restrict__ b1,
    const unsigned short* __restrict__ w2t,    // [n][k] bf16
    const float* __restrict__ b2,
    unsigned short* __restrict__ zb_out,       // bf16 out (layers 0,1)
    float* __restrict__ f_out) {               // f32 out (last layer) or null
  __shared__ alignas(16) unsigned char Ht[16 * 256];   // h = z+agg, swizzled bf16
  __shared__ alignas(16) unsigned char H2[16 * 256];   // relu(h@w1+b1), swizzled
  const int lane = threadIdx.x & 63;
  const int wv = threadIdx.x >> 6;             // 0..7
  const int nb = blockIdx.x * 16;
  const int hf = lane >> 4;        // which edge within a 4-edge chunk
  const int cs = lane & 15;        // 16B column-slot within a 256B row

  // ---- aggregation: wave wv owns rows {2wv, 2wv+1}, interleaved ----
  {
    const int r0 = wv * 2, r1 = r0 + 1;
    const int nodeA = __builtin_amdgcn_readfirstlane(nb + r0);
    const int nodeB = __builtin_amdgcn_readfirstlane(nb + r1);
    const int dgA = deg[nodeA], dgB = deg[nodeB];
    const unsigned short* cbA = col_ell + nodeA * CAP;
    const unsigned short* cbB = col_ell + nodeB * CAP;
    const int nch = (max(dgA, dgB) + 3) >> 2;
    float a0 = 0.f, a1 = 0.f, a2 = 0.f, a3 = 0.f;
    float a4 = 0.f, a5 = 0.f, a6 = 0.f, a7 = 0.f;
    float c0 = 0.f, c1 = 0.f, c2 = 0.f, c3 = 0.f;
    float c4 = 0.f, c5 = 0.f, c6 = 0.f, c7 = 0.f;
#pragma unroll 4
    for (int c = 0; c < nch; ++c) {
      int slot = c * 4 + hf;
      int idxA = (slot < dgA) ? (int)cbA[slot] : NN;
      int idxB = (slot < dgB) ? (int)cbB[slot] : NN;
      uint4 u = zb4[(size_t)idxA * 16 + cs];
      uint4 v = zb4[(size_t)idxB * 16 + cs];
      a0 += bflo(u.x); a1 += bfhi(u.x);
      a2 += bflo(u.y); a3 += bfhi(u.y);
      a4 += bflo(u.z); a5 += bfhi(u.z);
      a6 += bflo(u.w); a7 += bfhi(u.w);
      c0 += bflo(v.x); c1 += bfhi(v.x);
      c2 += bflo(v.y); c3 += bfhi(v.y);
      c4 += bflo(v.z); c5 += bfhi(v.z);
      c6 += bflo(v.w); c7 += bfhi(v.w);
    }
    // butterfly: lanes l, l^16, l^32, l^48 share columns -> all lanes get totals
    a0 += __shfl_xor(a0, 16); a1 += __shfl_xor(a1, 16);
    a2 += __shfl_xor(a2, 16); a3 += __shfl_xor(a3, 16);
    a4 += __shfl_xor(a4, 16); a5 += __shfl_xor(a5, 16);
    a6 += __shfl_xor(a6, 16); a7 += __shfl_xor(a7, 16);
    c0 += __shfl_xor(c0, 16); c1 += __shfl_xor(c1, 16);
    c2 += __shfl_xor(c2, 16); c3 += __shfl_xor(c3, 16);
    c4 += __shfl_xor(c4, 16); c5 += __shfl_xor(c5, 16);
    c6 += __shfl_xor(c6, 16); c7 += __shfl_xor(c7, 16);
    a0 += __shfl_xor(a0, 32); a1 += __shfl_xor(a1, 32);
    a2 += __shfl_xor(a2, 32); a3 += __shfl_xor(a3, 32);
    a4 += __shfl_xor(a4, 32); a5 += __shfl_xor(a5, 32);
    a6 += __shfl_xor(a6, 32); a7 += __shfl_xor(a7, 32);
    c0 += __shfl_xor(c0, 32); c1 += __shfl_xor(c1, 32);
    c2 += __shfl_xor(c2, 32); c3 += __shfl_xor(c3, 32);
    c4 += __shfl_xor(c4, 32); c5 += __shfl_xor(c5, 32);
    c6 += __shfl_xor(c6, 32); c7 += __shfl_xor(c7, 32);
    // self terms
    uint4 sA = zb4[(size_t)nodeA * 16 + cs];
    uint4 sB = zb4[(size_t)nodeB * 16 + cs];
    a0 += bflo(sA.x); a1 += bfhi(sA.x);
    a2 += bflo(sA.y); a3 += bfhi(sA.y);
    a4 += bflo(sA.z); a5 += bfhi(sA.z);
    a6 += bflo(sA.w); a7 += bfhi(sA.w);
    c0 += bflo(sB.x); c1 += bfhi(sB.x);
    c2 += bflo(sB.y); c3 += bfhi(sB.y);
    c4 += bflo(sB.z); c5 += bfhi(sB.z);
    c6 += bflo(sB.w); c7 += bfhi(sB.w);
    if (hf == 0) {
      uint4 p;
      p.x = packbf(a0, a1); p.y = packbf(a2, a3);
      p.z = packbf(a4, a5); p.w = packbf(a6, a7);
      *reinterpret_cast<uint4*>(&Ht[(r0 * 256 + cs * 16) ^ ((r0 & 7) << 4)]) = p;
    } else if (hf == 1) {
      uint4 p;
      p.x = packbf(c0, c1); p.y = packbf(c2, c3);
      p.z = packbf(c4, c5); p.w = packbf(c6, c7);
      *reinterpret_cast<uint4*>(&Ht[(r1 * 256 + cs * 16) ^ ((r1 & 7) << 4)]) = p;
    }
  }
  __syncthreads();

  const int ar = lane & 15;        // A row / B col / C col
  const int kg = lane >> 4;        // k-group 0..3
  const int crb = kg * 4;          // C/D row base

  // ---- GEMM1: wave's N-tile nt = wv ----
  short8 a[4];
#pragma unroll
  for (int ks = 0; ks < 4; ++ks) {
    int byte = (ar * 256 + (ks * 32 + kg * 8) * 2) ^ ((ar & 7) << 4);
    a[ks] = *reinterpret_cast<const short8*>(&Ht[byte]);
  }
  f32x4 acc = (f32x4){0.f, 0.f, 0.f, 0.f};
#pragma unroll
  for (int ks = 0; ks < 4; ++ks) {
    short8 b = *reinterpret_cast<const short8*>(&w1t[(wv * 16 + ar) * D + ks * 32 + kg * 8]);
    acc = __builtin_amdgcn_mfma_f32_16x16x32_bf16(a[ks], b, acc, 0, 0, 0);
  }
  {
    int col = wv * 16 + ar;
    float bias = b1[col];
#pragma unroll
    for (int j = 0; j < 4; ++j) {
      int r = crb + j;
      float v = fmaxf(acc[j] + bias, 0.f);
      int byte = (r * 256 + col * 2) ^ ((r & 7) << 4);
      *reinterpret_cast<unsigned short*>(&H2[byte]) = f2bu(v);
    }
  }
  __syncthreads();

  // ---- GEMM2 ----
  short8 a2[4];
#pragma unroll
  for (int ks = 0; ks < 4; ++ks) {
    int byte = (ar * 256 + (ks * 32 + kg * 8) * 2) ^ ((ar & 7) << 4);
    a2[ks] = *reinterpret_cast<const short8*>(&H2[byte]);
  }
  acc = (f32x4){0.f, 0.f, 0.f, 0.f};
#pragma unroll
  for (int ks = 0; ks < 4; ++ks) {
    short8 b = *reinterpret_cast<const short8*>(&w2t[(wv * 16 + ar) * D + ks * 32 + kg * 8]);
    acc = __builtin_amdgcn_mfma_f32_16x16x32_bf16(a2[ks], b, acc, 0, 0, 0);
  }
  {
    int col = wv * 16 + ar;
    float bias = b2[col];
    if (f_out != nullptr) {
#pragma unroll
      for (int j = 0; j < 4; ++j) {
        int row = nb + crb + j;
        f_out[(size_t)row * D + col] = fmaxf(acc[j] + bias, 0.f);
      }
    } else {
#pragma unroll
      for (int j = 0; j < 4; ++j) {
        int row = nb + crb + j;
        zb_out[(size_t)row * D + col] = f2bu(fmaxf(acc[j] + bias, 0.f));
      }
    }
  }
}

extern "C" void kernel_launch(void* const* d_in, const int* in_sizes, int n_in,
                              void* d_out, int out_size, void* d_ws, size_t ws_size,
                              hipStream_t stream) {
  const float* x = (const float*)d_in[0];
  const int* ei = (const int*)d_in[1];
  const float* w1[3] = {(const float*)d_in[2], (const float*)d_in[6], (const float*)d_in[10]};
  const float* b1[3] = {(const float*)d_in[3], (const float*)d_in[7], (const float*)d_in[11]};
  const float* w2[3] = {(const float*)d_in[4], (const float*)d_in[8], (const float*)d_in[12]};
  const float* b2[3] = {(const float*)d_in[5], (const float*)d_in[9], (const float*)d_in[13]};
  float* out = (float*)d_out;

  char* wsb = (char*)d_ws;
  size_t off = 0;
  auto alloc = [&](size_t bytes) -> void* {
    void* p = wsb + off;
    off += (bytes + 255) & ~(size_t)255;
    return p;
  };
  unsigned short* zbA = (unsigned short*)alloc((size_t)(NN + 1) * D * 2);
  unsigned short* zbB = (unsigned short*)alloc((size_t)(NN + 1) * D * 2);
  unsigned short* wt  = (unsigned short*)alloc((size_t)6 * D * D * 2);
  int* fill = (int*)alloc((size_t)NDPAD * 4);
  unsigned short* col_ell = (unsigned short*)alloc((size_t)NDPAD * CAP * 2);

  prep_kernel<<<PREP_BLK, 256, 0, stream>>>(
      (const float4*)x, (uint2*)zbA, (uint2*)zbB, w1[0], w2[0], w1[1], w2[1], w1[2], w2[2],
      wt, fill);
  csr_kernel<<<(NE / ECHUNK) * 8, 256, 0, stream>>>(ei, fill, col_ell);
  sort_kernel<<<NN / 8, 512, 0, stream>>>(fill, col_ell);

  const unsigned short* zin = zbA;
  unsigned short* zout = zbB;
  for (int l = 0; l < 3; ++l) {
    layer_kernel<<<NN / 16, 512, 0, stream>>>(
        (const uint4*)zin, fill, col_ell,
        wt + (size_t)(2 * l) * D * D, b1[l],
        wt + (size_t)(2 * l + 1) * D * D, b2[l],
        zout, (l == 2) ? out : nullptr);
    const unsigned short* t = zin;
    zin = zout;
    zout = (unsigned short*)t;
  }
}